// Round 1
// baseline (333.495 us; speedup 1.0000x reference)
//
#include <hip/hip_runtime.h>
#include <stdint.h>

// LearnedStructuredAttentionSB: S=2048, B=4, H=1024
//   Q = x@Wq^T + bq ; K = x@Wk^T + bk ; V = x@Wv^T + bv   (rows r = s*B+b)
//   scores[b,q,k] = Q.K/32 + beta*ssm ; attn = softmax ; out = attn@V  -> [S,B,H]

#define S_LEN 2048
#define BATCH 4
#define HDIM  1024

typedef unsigned short u16;
typedef float f32x4  __attribute__((ext_vector_type(4)));
typedef short bf16x8 __attribute__((ext_vector_type(8)));
typedef u16   u16x4  __attribute__((ext_vector_type(4)));

__device__ __forceinline__ u16 f2bf(float f) {  // round-to-nearest-even f32->bf16
  union { float f; uint32_t u; } c; c.f = f;
  uint32_t u = c.u;
  u += 0x7fffu + ((u >> 16) & 1u);
  return (u16)(u >> 16);
}

// ---------------- cast fp32 -> bf16, vectorized ----------------
__global__ __launch_bounds__(256) void cast_f32_bf16(const float* __restrict__ src,
                                                     u16* __restrict__ dst, int n4) {
  int i = blockIdx.x * 256 + threadIdx.x;
  if (i >= n4) return;
  f32x4 v = *(const f32x4*)(src + (size_t)i * 4);
  u16x4 o;
  o.x = f2bf(v.x); o.y = f2bf(v.y); o.z = f2bf(v.z); o.w = f2bf(v.w);
  *(u16x4*)(dst + (size_t)i * 4) = o;
}

// ---------------- generic B^T GEMM, 128x128 tile, BK=64 ----------------
// C[M][N] = A[M][K] * B[N][K]^T  (bf16 inputs, fp32 accum)
// MODE 0: C bf16 = (acc + E[col]) * scale          (projection + bias)
// MODE 1: C f32  = acc + (*beta_p) * E[row*ldE+col] (scores + beta*ssm)
// MODE 2: C f32  = acc                              (PV)
// blockIdx.z applies batch strides bsA/bsB/bsC/bsE (element units).
template <int MODE>
__global__ __launch_bounds__(256)
void gemm_bt(const u16* __restrict__ A, int lda, long bsA,
             const u16* __restrict__ Bm, int ldb, long bsB,
             void* __restrict__ Cp, int ldc, long bsC,
             int K,
             const float* __restrict__ E, int ldE, long bsE,
             const float* __restrict__ beta_p, float scale) {
  __shared__ u16 lA[128 * 64];
  __shared__ u16 lB[128 * 64];
  const int t = threadIdx.x;
  const int lane = t & 63;
  const int wave = t >> 6;
  const int wm = wave & 1, wn = wave >> 1;     // 2x2 waves of 64x64
  const int z = blockIdx.z;
  A  += (size_t)z * (size_t)bsA;
  Bm += (size_t)z * (size_t)bsB;
  const size_t brow = (size_t)blockIdx.x * 128;
  const size_t bcol = (size_t)blockIdx.y * 128;

  f32x4 acc[4][4] = {};

  // Staging geometry: tile is [128 rows][64 bf16] = 128B rows, 8 chunks of 16B.
  // LDS dest is LINEAR (global_load_lds writes base+lane*16); bank-conflict fix is
  // applied by swizzling the GLOBAL source chunk (involution chunk ^= row&7) and
  // reading frags at the same swizzle (rule #21).
  int rowT[4], scT[4];
#pragma unroll
  for (int j = 0; j < 4; ++j) {
    int o = j * 4096 + t * 16;       // byte offset into 16KB tile
    int row = o >> 7;                // 128B per row
    int ch = (o >> 4) & 7;           // 16B chunk within row
    rowT[j] = row;
    scT[j] = (ch ^ (row & 7)) * 8;   // swizzled source column (elements)
  }
  const int ldsw = wave * 512;       // wave-uniform LDS base (u16 units) = 1KB/wave

  const u16* pA[4];
  const u16* pB[4];
#pragma unroll
  for (int j = 0; j < 4; ++j) {
    pA[j] = A  + (brow + rowT[j]) * (size_t)lda + scT[j];
    pB[j] = Bm + (bcol + rowT[j]) * (size_t)ldb + scT[j];
  }

  // Frag-read LDS offsets (u16 units), swizzle-matched
  int offA[2][4], offB[2][4];
#pragma unroll
  for (int ks = 0; ks < 2; ++ks) {
#pragma unroll
    for (int i = 0; i < 4; ++i) {
      int ra = wm * 64 + i * 16 + (lane & 15);
      int rb = wn * 64 + i * 16 + (lane & 15);
      int c = ks * 4 + (lane >> 4);
      offA[ks][i] = ra * 64 + ((c ^ (ra & 7)) * 8);
      offB[ks][i] = rb * 64 + ((c ^ (rb & 7)) * 8);
    }
  }

  for (int k0 = 0; k0 < K; k0 += 64) {
    if (k0) __syncthreads();  // previous tile fully consumed before overwrite
#pragma unroll
    for (int j = 0; j < 4; ++j)
      __builtin_amdgcn_global_load_lds(
          (const __attribute__((address_space(1))) void*)(pA[j] + k0),
          (__attribute__((address_space(3))) void*)(lA + j * 2048 + ldsw), 16, 0, 0);
#pragma unroll
    for (int j = 0; j < 4; ++j)
      __builtin_amdgcn_global_load_lds(
          (const __attribute__((address_space(1))) void*)(pB[j] + k0),
          (__attribute__((address_space(3))) void*)(lB + j * 2048 + ldsw), 16, 0, 0);
    __syncthreads();  // compiler drains vmcnt(0) before barrier

#pragma unroll
    for (int ks = 0; ks < 2; ++ks) {
      bf16x8 af[4], bf_[4];
#pragma unroll
      for (int mi = 0; mi < 4; ++mi) af[mi] = *(const bf16x8*)(lA + offA[ks][mi]);
#pragma unroll
      for (int ni = 0; ni < 4; ++ni) bf_[ni] = *(const bf16x8*)(lB + offB[ks][ni]);
#pragma unroll
      for (int mi = 0; mi < 4; ++mi)
#pragma unroll
        for (int ni = 0; ni < 4; ++ni)
          acc[mi][ni] = __builtin_amdgcn_mfma_f32_16x16x32_bf16(af[mi], bf_[ni],
                                                                acc[mi][ni], 0, 0, 0);
    }
  }

  // Epilogue. C/D frag: col = lane&15, row = (lane>>4)*4 + reg  [m89-verified]
  const int r0 = (int)brow + wm * 64 + ((lane >> 4) << 2);
  const int c0 = (int)bcol + wn * 64 + (lane & 15);
  if constexpr (MODE == 0) {
    u16* C = (u16*)Cp;
#pragma unroll
    for (int ni = 0; ni < 4; ++ni) {
      int cc = c0 + ni * 16;
      float bv = E[cc];
#pragma unroll
      for (int mi = 0; mi < 4; ++mi)
#pragma unroll
        for (int q = 0; q < 4; ++q)
          C[(size_t)(r0 + mi * 16 + q) * ldc + cc] = f2bf((acc[mi][ni][q] + bv) * scale);
    }
  } else if constexpr (MODE == 1) {
    float* C = (float*)Cp + (size_t)z * (size_t)bsC;
    const float* Ez = E + (size_t)z * (size_t)bsE;
    const float beta = *beta_p;
#pragma unroll
    for (int ni = 0; ni < 4; ++ni) {
      int cc = c0 + ni * 16;
#pragma unroll
      for (int mi = 0; mi < 4; ++mi)
#pragma unroll
        for (int q = 0; q < 4; ++q) {
          int rr = r0 + mi * 16 + q;
          C[(size_t)rr * ldc + cc] = acc[mi][ni][q] + beta * Ez[(size_t)rr * ldE + cc];
        }
    }
  } else {
    float* C = (float*)Cp + (size_t)z * (size_t)bsC;
#pragma unroll
    for (int ni = 0; ni < 4; ++ni) {
      int cc = c0 + ni * 16;
#pragma unroll
      for (int mi = 0; mi < 4; ++mi)
#pragma unroll
        for (int q = 0; q < 4; ++q)
          C[(size_t)(r0 + mi * 16 + q) * ldc + cc] = acc[mi][ni][q];
    }
  }
}

// ---------------- V transpose: Vb[s*B+b][h] -> Vt[b][h][s] ----------------
__global__ __launch_bounds__(256) void transpose_v(const u16* __restrict__ V,
                                                   u16* __restrict__ Vt) {
  __shared__ u16 tile[64][68];
  const int b = blockIdx.z;
  const int s0 = blockIdx.x << 6, h0 = blockIdx.y << 6;
  const int t = threadIdx.x;
#pragma unroll
  for (int i = 0; i < 4; ++i) {
    int sl = (t >> 4) + i * 16;
    int hq = (t & 15) << 2;
    u16x4 v = *(const u16x4*)&V[((size_t)(s0 + sl) * BATCH + b) * HDIM + h0 + hq];
    *(u16x4*)&tile[sl][hq] = v;
  }
  __syncthreads();
#pragma unroll
  for (int i = 0; i < 4; ++i) {
    int hl = (t >> 4) + i * 16;
    int sq = (t & 15) << 2;
    u16x4 v;
    v.x = tile[sq + 0][hl]; v.y = tile[sq + 1][hl];
    v.z = tile[sq + 2][hl]; v.w = tile[sq + 3][hl];
    *(u16x4*)&Vt[((size_t)b * HDIM + h0 + hl) * S_LEN + s0 + sq] = v;
  }
}

// ---------------- row softmax, bf16 written in place over fp32 row ----------------
__global__ __launch_bounds__(256) void softmax_row(float* __restrict__ scores) {
  const size_t row = blockIdx.x;
  float* rp = scores + row * 2048;
  const int t = threadIdx.x;
  const int lane = t & 63, wave = t >> 6;
  f32x4 v0 = *(const f32x4*)(rp + t * 8);
  f32x4 v1 = *(const f32x4*)(rp + t * 8 + 4);
  float m = -3.0e38f;
#pragma unroll
  for (int i = 0; i < 4; ++i) m = fmaxf(m, fmaxf(v0[i], v1[i]));
#pragma unroll
  for (int off = 32; off > 0; off >>= 1) m = fmaxf(m, __shfl_xor(m, off));
  __shared__ float red[8];
  if (lane == 0) red[wave] = m;
  __syncthreads();
  m = fmaxf(fmaxf(red[0], red[1]), fmaxf(red[2], red[3]));
  float e[8], s = 0.f;
#pragma unroll
  for (int i = 0; i < 4; ++i) { e[i] = __expf(v0[i] - m); s += e[i]; }
#pragma unroll
  for (int i = 0; i < 4; ++i) { e[4 + i] = __expf(v1[i] - m); s += e[4 + i]; }
#pragma unroll
  for (int off = 32; off > 0; off >>= 1) s += __shfl_xor(s, off);
  if (lane == 0) red[4 + wave] = s;
  __syncthreads();
  s = (red[4] + red[5]) + (red[6] + red[7]);
  const float inv = 1.0f / s;
  u16* wp = (u16*)rp;  // safe: every thread's loads precede the barriers above
  u16x4 o0, o1;
  o0.x = f2bf(e[0] * inv); o0.y = f2bf(e[1] * inv);
  o0.z = f2bf(e[2] * inv); o0.w = f2bf(e[3] * inv);
  o1.x = f2bf(e[4] * inv); o1.y = f2bf(e[5] * inv);
  o1.z = f2bf(e[6] * inv); o1.w = f2bf(e[7] * inv);
  *(u16x4*)(wp + t * 8) = o0;
  *(u16x4*)(wp + t * 8 + 4) = o1;
}

extern "C" void kernel_launch(void* const* d_in, const int* in_sizes, int n_in,
                              void* d_out, int out_size, void* d_ws, size_t ws_size,
                              hipStream_t stream) {
  const float* x    = (const float*)d_in[0];
  const float* ssm  = (const float*)d_in[1];
  const float* Wq   = (const float*)d_in[2];
  const float* bq   = (const float*)d_in[3];
  const float* Wk   = (const float*)d_in[4];
  const float* bk   = (const float*)d_in[5];
  const float* Wv   = (const float*)d_in[6];
  const float* bv   = (const float*)d_in[7];
  const float* beta = (const float*)d_in[8];
  float* out = (float*)d_out;

  char* p = (char*)d_ws;
  u16* xb  = (u16*)p; p += (size_t)8192 * 1024 * 2;
  u16* wqb = (u16*)p; p += (size_t)1024 * 1024 * 2;
  u16* wkb = (u16*)p; p += (size_t)1024 * 1024 * 2;
  u16* wvb = (u16*)p; p += (size_t)1024 * 1024 * 2;
  u16* Qs  = (u16*)p; p += (size_t)8192 * 1024 * 2;   // (Q+bq)/32, bf16, [S*B][H]
  u16* Kb  = (u16*)p; p += (size_t)8192 * 1024 * 2;
  u16* Vb  = (u16*)p; p += (size_t)8192 * 1024 * 2;
  u16* Vt  = (u16*)p; p += (size_t)BATCH * HDIM * S_LEN * 2;  // [B][H][S]
  float* sc = (float*)p;  // [B][S][S] fp32; attn bf16 aliased in place after softmax

  // casts
  cast_f32_bf16<<<8192, 256, 0, stream>>>(x, xb, 2097152);
  cast_f32_bf16<<<1024, 256, 0, stream>>>(Wq, wqb, 262144);
  cast_f32_bf16<<<1024, 256, 0, stream>>>(Wk, wkb, 262144);
  cast_f32_bf16<<<1024, 256, 0, stream>>>(Wv, wvb, 262144);

  // projections: M=8192, N=1024, K=1024
  dim3 gp(64, 8, 1);
  gemm_bt<0><<<gp, 256, 0, stream>>>(xb, 1024, 0, wqb, 1024, 0, Qs, 1024, 0, 1024,
                                     bq, 0, 0, nullptr, 0.03125f);
  gemm_bt<0><<<gp, 256, 0, stream>>>(xb, 1024, 0, wkb, 1024, 0, Kb, 1024, 0, 1024,
                                     bk, 0, 0, nullptr, 1.0f);
  gemm_bt<0><<<gp, 256, 0, stream>>>(xb, 1024, 0, wvb, 1024, 0, Vb, 1024, 0, 1024,
                                     bv, 0, 0, nullptr, 1.0f);

  transpose_v<<<dim3(32, 16, 4), 256, 0, stream>>>(Vb, Vt);

  // scores: per batch, M=N=2048, K=1024; A/B rows strided by B*H
  dim3 gs(16, 16, 4);
  gemm_bt<1><<<gs, 256, 0, stream>>>(Qs, 4096, 1024, Kb, 4096, 1024,
                                     sc, 2048, (long)2048 * 2048, 1024,
                                     ssm, 2048, (long)2048 * 2048, beta, 1.0f);

  softmax_row<<<8192, 256, 0, stream>>>(sc);

  // PV: per batch, M=2048(q), N=1024(h), K=2048(k); A=attn bf16 aliased (lda=4096),
  // B=Vt[b] (ldb=2048); C=out[s][b][h] (ldc=4096, batch offset b*1024)
  dim3 gv(16, 8, 4);
  gemm_bt<2><<<gv, 256, 0, stream>>>((const u16*)sc, 4096, 8388608,
                                     Vt, 2048, (long)HDIM * S_LEN,
                                     out, 4096, 1024, 2048,
                                     nullptr, 0, 0, nullptr, 1.0f);
}